// Round 4
// baseline (1414.750 us; speedup 1.0000x reference)
//
#include <hip/hip_runtime.h>
#include <hip/hip_bf16.h>

typedef __hip_bfloat16 bf16;
typedef __attribute__((ext_vector_type(8))) short bh8;   // 8 bf16 (MFMA A/B frag)
typedef __attribute__((ext_vector_type(4))) float f4;    // MFMA C/D frag

#define TOKENS 200704   // 16*112*112 = 4096 windows * 49
#define CDIM   192

__device__ __forceinline__ void gload16(const bf16* g, bf16* l) {
    __builtin_amdgcn_global_load_lds((const __attribute__((address_space(1))) void*)g,
                                     (__attribute__((address_space(3))) void*)l,
                                     16, 0, 0);
}

__device__ __forceinline__ void stv(float* p, float v) { *p = v; }
__device__ __forceinline__ void stv(bf16* p, float v)  { *p = __float2bfloat16(v); }

// window-row -> token index ((b,hs,ws) shifted back by +3)
__device__ __forceinline__ int row2tok(int row) {
    int win = row / 49, n = row - win * 49;
    int b = win >> 8, rem = win & 255;
    int hs = (rem >> 4) * 7 + n / 7;
    int wsx = (rem & 15) * 7 + n % 7;
    int hh = hs + 3; if (hh >= 112) hh -= 112;
    int ww = wsx + 3; if (ww >= 112) ww -= 112;
    return (b * 112 + hh) * 112 + ww;
}

// ---- fp32 -> bf16 weight conversion ----
__global__ void cvt_kernel(const float* __restrict__ s, bf16* __restrict__ d, int n) {
    int i = blockIdx.x * 256 + threadIdx.x;
    if (i < n) d[i] = __float2bfloat16(s[i]);
}

// ---- bias precompute: biasg[h][i][j] = rpb_table[rpi[i*49+j]][h] (fp32) ----
__global__ void bias_kernel(const int* __restrict__ rpi, const float* __restrict__ tab,
                            float* __restrict__ bg) {
    int idx = blockIdx.x * 256 + threadIdx.x;
    if (idx < 6 * 2401) {
        int h = idx / 2401, ij = idx - h * 2401;
        bg[idx] = tab[rpi[ij] * 6 + h];
    }
}

// ---- LayerNorm (fp32 in, bf16 out), gathered: dst[wrow] = LN(src[token(wrow)]) ----
__global__ __launch_bounds__(256)
void ln_kernel(const float* __restrict__ src, const float* __restrict__ gw,
               const float* __restrict__ bw, bf16* __restrict__ dst) {
    const int lane = threadIdx.x & 63;
    const int gwv  = (blockIdx.x * 256 + threadIdx.x) >> 6;
    const int nwv  = (gridDim.x * 256) >> 6;
    const float g0 = gw[lane], g1 = gw[lane + 64], g2 = gw[lane + 128];
    const float b0 = bw[lane], b1 = bw[lane + 64], b2 = bw[lane + 128];
    for (int row = gwv; row < TOKENS; row += nwv) {
        const float* p = src + (size_t)row2tok(row) * CDIM;
        float v0 = p[lane], v1 = p[lane + 64], v2 = p[lane + 128];
        float s = v0 + v1 + v2;
        float q = v0 * v0 + v1 * v1 + v2 * v2;
        #pragma unroll
        for (int o = 32; o; o >>= 1) { s += __shfl_xor(s, o, 64); q += __shfl_xor(q, o, 64); }
        float mean = s * (1.f / 192.f);
        float var  = q * (1.f / 192.f) - mean * mean;
        float rstd = rsqrtf(var + 1e-5f);
        bf16* d = dst + (size_t)row * CDIM;
        d[lane]       = __float2bfloat16((v0 - mean) * rstd * g0 + b0);
        d[lane + 64]  = __float2bfloat16((v1 - mean) * rstd * g1 + b1);
        d[lane + 128] = __float2bfloat16((v2 - mean) * rstd * g2 + b2);
    }
}

// ---- GEMM: C[M,N] = A[M,K] @ W[N,K]^T + bias (A,W bf16; bias/res fp32) ----
// EPI 0: plain->bf16 (qkv).  EPI 1: proj: scatter+residual->fp32 x1; FUSELN adds
//        LayerNorm over each row -> hbuf (bf16, window-ordered).
// BM=128, BN=192, BK=32; 4 waves, each 64x96 (4x6 frags 16x16x32)
template<int EPI, int FUSELN, typename OutT>
__global__ __launch_bounds__(256)
void gemm_bt(const bf16* __restrict__ A, const bf16* __restrict__ W,
             const float* __restrict__ bias, OutT* out,
             const float* res, int N, int K,
             const float* __restrict__ g2, const float* __restrict__ b2g,
             bf16* __restrict__ hbuf) {
    __shared__ __align__(16) bf16 As[128 * 32];
    __shared__ __align__(16) bf16 Bs[192 * 32];
    __shared__ float rsum[FUSELN ? 128 : 1][2], rsq[FUSELN ? 128 : 1][2];
    const int tid = threadIdx.x, wid = tid >> 6, lane = tid & 63;
    const int mbase = blockIdx.y * 128, nbase = blockIdx.x * 192;
    const int wm = wid >> 1, wn = wid & 1;
    const int r = lane & 15, ko = (lane >> 4) * 8;
    const bf16* Ab = A + (size_t)mbase * K;
    const bf16* Wb = W + (size_t)nbase * K;
    f4 acc[4][6] = {};
    const int cbase = wid * 64 + lane;
    for (int k0 = 0; k0 < K; k0 += 32) {
        #pragma unroll
        for (int p = 0; p < 2; ++p) {   // A tile: 128x32 = 512 chunks of 16B
            int ci = p * 256 + cbase;
            gload16(Ab + (size_t)(ci >> 2) * K + (k0 + ((ci & 3) << 3)),
                    &As[(p * 256 + wid * 64) * 8]);
        }
        #pragma unroll
        for (int p = 0; p < 3; ++p) {   // B tile: 192x32 = 768 chunks of 16B
            int ci = p * 256 + cbase;
            gload16(Wb + (size_t)(ci >> 2) * K + (k0 + ((ci & 3) << 3)),
                    &Bs[(p * 256 + wid * 64) * 8]);
        }
        __syncthreads();
        bh8 af[4], bfr[6];
        #pragma unroll
        for (int i = 0; i < 4; ++i)
            af[i] = *(const bh8*)&As[(wm * 64 + i * 16 + r) * 32 + ko];
        #pragma unroll
        for (int j = 0; j < 6; ++j)
            bfr[j] = *(const bh8*)&Bs[(wn * 96 + j * 16 + r) * 32 + ko];
        #pragma unroll
        for (int i = 0; i < 4; ++i)
            #pragma unroll
            for (int j = 0; j < 6; ++j)
                acc[i][j] = __builtin_amdgcn_mfma_f32_16x16x32_bf16(af[i], bfr[j], acc[i][j], 0, 0, 0);
        __syncthreads();
    }
    // epilogue: C/D frag layout col = lane&15, row = (lane>>4)*4 + reg
    const int cr = lane >> 4, cc = lane & 15;
    if constexpr (EPI == 0) {
        #pragma unroll
        for (int i = 0; i < 4; ++i) {
            #pragma unroll
            for (int j = 0; j < 6; ++j) {
                int ncol = nbase + wn * 96 + j * 16 + cc;
                float bv = bias[ncol];
                #pragma unroll
                for (int rr = 0; rr < 4; ++rr) {
                    int row = mbase + wm * 64 + i * 16 + cr * 4 + rr;
                    stv(&out[(size_t)row * N + ncol], acc[i][j][rr] + bv);
                }
            }
        }
    } else {
        // pass 1: v = acc + bias + res(x) -> x1 (token scatter); row stats
        #pragma unroll
        for (int i = 0; i < 4; ++i) {
            size_t dstRow[4];
            float ps[4], pq[4];
            #pragma unroll
            for (int rr = 0; rr < 4; ++rr) {
                int row = mbase + wm * 64 + i * 16 + cr * 4 + rr;
                dstRow[rr] = (size_t)row2tok(row) * CDIM;
                ps[rr] = 0.f; pq[rr] = 0.f;
            }
            #pragma unroll
            for (int j = 0; j < 6; ++j) {
                int ncol = nbase + wn * 96 + j * 16 + cc;
                float bv = bias[ncol];
                #pragma unroll
                for (int rr = 0; rr < 4; ++rr) {
                    float v = acc[i][j][rr] + bv + res[dstRow[rr] + ncol];
                    stv(&out[dstRow[rr] + ncol], v);
                    acc[i][j][rr] = v;
                    ps[rr] += v; pq[rr] += v * v;
                }
            }
            if constexpr (FUSELN) {
                #pragma unroll
                for (int rr = 0; rr < 4; ++rr) {
                    float s = ps[rr], q = pq[rr];
                    #pragma unroll
                    for (int o = 1; o < 16; o <<= 1) { s += __shfl_xor(s, o, 64); q += __shfl_xor(q, o, 64); }
                    if (cc == 0) {
                        int rl = wm * 64 + i * 16 + cr * 4 + rr;
                        rsum[rl][wn] = s; rsq[rl][wn] = q;
                    }
                }
            }
        }
        if constexpr (FUSELN) {
            __syncthreads();
            #pragma unroll
            for (int i = 0; i < 4; ++i) {
                #pragma unroll
                for (int j = 0; j < 6; ++j) {
                    int ncol = nbase + wn * 96 + j * 16 + cc;
                    float gv = g2[ncol], bvv = b2g[ncol];
                    #pragma unroll
                    for (int rr = 0; rr < 4; ++rr) {
                        int rl = wm * 64 + i * 16 + cr * 4 + rr;
                        float mean = (rsum[rl][0] + rsum[rl][1]) * (1.f / 192.f);
                        float var  = (rsq[rl][0] + rsq[rl][1]) * (1.f / 192.f) - mean * mean;
                        float rstd = rsqrtf(var + 1e-5f);
                        hbuf[(size_t)(mbase + rl) * CDIM + ncol] =
                            __float2bfloat16((acc[i][j][rr] - mean) * rstd * gv + bvv);
                    }
                }
            }
        }
    }
}

// ---- attention: one wave per (local window, head); in-register softmax ----
__global__ __launch_bounds__(256)
void attn_kernel(const bf16* __restrict__ qkv, const float* __restrict__ mask,
                 const float* __restrict__ biasg, bf16* __restrict__ out, int woff) {
    __shared__ float kv[4][2][49][32];   // 50176 B
    const int wid = threadIdx.x >> 6, lane = threadIdx.x & 63;
    const int task = blockIdx.x * 4 + wid;
    const int win = task / 6;                 // local window within chunk
    const int head = task - win * 6;
    const bf16* base = qkv + (size_t)win * 49 * 576 + head * 32;
    for (int idx = lane; idx < 49 * 32; idx += 64) {
        int j = idx >> 5, d = idx & 31;
        kv[wid][0][j][d] = __bfloat162float(base[j * 576 + 192 + d]);  // K
        kv[wid][1][j][d] = __bfloat162float(base[j * 576 + 384 + d]);  // V
    }
    __syncthreads();
    const int i = lane < 49 ? lane : 48;
    float q[32];
    #pragma unroll
    for (int d = 0; d < 32; ++d)
        q[d] = __bfloat162float(base[i * 576 + d]) * 0.17677669529663689f;  // 1/sqrt(32)
    const float* bg = biasg + head * 2401 + i * 49;
    const float* mk = mask + (size_t)((win + woff) & 255) * 2401 + i * 49;
    float s[49];
    float mx = -1e30f;
    #pragma unroll
    for (int j = 0; j < 49; ++j) {
        float a = 0.f;
        #pragma unroll
        for (int d = 0; d < 32; ++d) a += q[d] * kv[wid][0][j][d];
        a += bg[j] + mk[j];
        s[j] = a;
        mx = fmaxf(mx, a);
    }
    float sum = 0.f;
    #pragma unroll
    for (int j = 0; j < 49; ++j) { s[j] = __expf(s[j] - mx); sum += s[j]; }
    const float inv = 1.f / sum;
    float o[32];
    #pragma unroll
    for (int d = 0; d < 32; ++d) o[d] = 0.f;
    #pragma unroll
    for (int j = 0; j < 49; ++j) {
        float p = s[j] * inv;
        #pragma unroll
        for (int d = 0; d < 32; ++d) o[d] += p * kv[wid][1][j][d];
    }
    if (lane < 49) {
        bf16* op = out + ((size_t)win * 49 + lane) * CDIM + head * 32;
        #pragma unroll
        for (int d = 0; d < 32; ++d) op[d] = __float2bfloat16(o[d]);
    }
}

// ---- fused MLP: out[tok] = x1[tok] + fc2(gelu(fc1(hbuf[wrow]))) ----
// 64-row blocks, 32 KiB LDS (As 24K + Hs 8K swizzled) -> ~4 blocks/CU.
// 12 chunks of 64 fc1-cols: GEMM1(64x64xK192) -> GELU -> Hs -> GEMM2 acc (64x192xK64).
// Weights as 16B lane frags from global (L2-resident, 588 KB/block).
__global__ __launch_bounds__(256)
void mlp_kernel(const bf16* __restrict__ Aht, const bf16* __restrict__ w1,
                const float* __restrict__ b1, const bf16* __restrict__ w2,
                const float* __restrict__ b2, float* __restrict__ out) {
    __shared__ __align__(16) bf16 As[6][64][32];   // 24576 B
    __shared__ __align__(16) bf16 Hs[64][64];      // 8192 B, XOR-swizzled groups
    const int tid = threadIdx.x, wid = tid >> 6, lane = tid & 63;
    const int r = lane & 15, q = lane >> 4, ko = q * 8;
    const int mbase = blockIdx.x * 64;
    const int l = wid * 64 + lane, arow = l >> 2, ag = l & 3;
    #pragma unroll
    for (int ks = 0; ks < 6; ++ks)
        gload16(Aht + (size_t)(mbase + arow) * 192 + ks * 32 + ag * 8,
                &As[ks][0][0] + (size_t)(wid * 64) * 8);
    __syncthreads();
    f4 acc2[12] = {};
    for (int c = 0; c < 12; ++c) {
        const int cb = c * 64;
        f4 acc1[4] = {};
        #pragma unroll
        for (int ks = 0; ks < 6; ++ks) {
            bh8 bfr = *(const bh8*)&w1[(size_t)(cb + wid * 16 + r) * 192 + ks * 32 + ko];
            #pragma unroll
            for (int i = 0; i < 4; ++i) {
                bh8 af = *(const bh8*)&As[ks][i * 16 + r][ko];
                acc1[i] = __builtin_amdgcn_mfma_f32_16x16x32_bf16(af, bfr, acc1[i], 0, 0, 0);
            }
        }
        float b1v = b1[cb + wid * 16 + r];
        __syncthreads();   // prior GEMM2 reads of Hs done
        #pragma unroll
        for (int i = 0; i < 4; ++i) {
            #pragma unroll
            for (int rr = 0; rr < 4; ++rr) {
                int row = i * 16 + q * 4 + rr;
                int col = wid * 16 + r;
                float v = acc1[i][rr] + b1v;
                float u = v * (0.7978845608f + 0.0356774081f * v * v);  // sqrt(2/pi)*(v+0.044715v^3)
                float e = __expf(2.f * u);
                float t = 1.f - 2.f / (e + 1.f);                        // tanh(u)
                Hs[row][col ^ ((row & 7) << 3)] = __float2bfloat16(0.5f * v * (1.f + t));
            }
        }
        __syncthreads();   // Hs visible
        #pragma unroll
        for (int ks = 0; ks < 2; ++ks) {
            const int hrow = wid * 16 + r;
            bh8 af = *(const bh8*)&Hs[hrow][(ks * 32 + ko) ^ ((hrow & 7) << 3)];
            #pragma unroll
            for (int j = 0; j < 12; ++j) {
                bh8 bfr = *(const bh8*)&w2[(size_t)(j * 16 + r) * 768 + cb + ks * 32 + ko];
                acc2[j] = __builtin_amdgcn_mfma_f32_16x16x32_bf16(af, bfr, acc2[j], 0, 0, 0);
            }
        }
    }
    int tok[4];
    #pragma unroll
    for (int rr = 0; rr < 4; ++rr)
        tok[rr] = row2tok(mbase + wid * 16 + q * 4 + rr);
    #pragma unroll
    for (int j = 0; j < 12; ++j) {
        float bv = b2[j * 16 + r];
        #pragma unroll
        for (int rr = 0; rr < 4; ++rr) {
            size_t idx = (size_t)tok[rr] * 192 + j * 16 + r;
            out[idx] = acc2[j][rr] + bv + out[idx];
        }
    }
}

extern "C" void kernel_launch(void* const* d_in, const int* in_sizes, int n_in,
                              void* d_out, int out_size, void* d_ws, size_t ws_size,
                              hipStream_t stream) {
    const float* x     = (const float*)d_in[0];
    const float* mask  = (const float*)d_in[1];
    const int*   rpi   = (const int*)d_in[2];
    const float* rpb   = (const float*)d_in[3];
    const float* n1g   = (const float*)d_in[4];
    const float* n1b   = (const float*)d_in[5];
    const float* qkvw  = (const float*)d_in[6];
    const float* qkvb  = (const float*)d_in[7];
    const float* projw = (const float*)d_in[8];
    const float* projb = (const float*)d_in[9];
    const float* n2g   = (const float*)d_in[10];
    const float* n2b   = (const float*)d_in[11];
    const float* fc1w  = (const float*)d_in[12];
    const float* fc1b  = (const float*)d_in[13];
    const float* fc2w  = (const float*)d_in[14];
    const float* fc2b  = (const float*)d_in[15];

    // ws layout:
    //  [0, 77,070,336)            attno bf16 (window order); non-fused: hbuf reuses this
    //  [77,070,336, 77,131,776)   biasg fp32
    //  [77,131,776, 78,016,512)   bf16 weights (wq|wp|w1|w2)
    //  [78,016,512, +cw*56448)    qbuf (qkv chunk);  fused path: hbuf bf16 77,070,336 B
    //                             (qbuf lifetime ends before hbuf written)
    char* ws = (char*)d_ws;
    bf16*  attno  = (bf16*)ws;
    float* biasg  = (float*)(ws + 77070336);
    bf16*  wq     = (bf16*)(ws + 77131776);
    bf16*  wp     = (bf16*)(ws + 77352960);
    bf16*  w1     = (bf16*)(ws + 77426688);
    bf16*  w2     = (bf16*)(ws + 77721600);
    bf16*  qbuf   = (bf16*)(ws + 78016512);
    bf16*  xw     = (bf16*)d_out;    // LN1 out lives in d_out until proj overwrites it
    float* x1     = (float*)d_out;

    const bool fuse = ws_size >= 155086848ull;   // hbuf fits after weights
    bf16* hbuf = fuse ? (bf16*)(ws + 78016512) : (bf16*)ws;

    int cw = 1024;
    while (cw > 128 && 78016512ull + (size_t)cw * 56448 > ws_size) cw >>= 1;
    const int nchunks = 4096 / cw;

    cvt_kernel<<<432, 256, 0, stream>>>(qkvw, wq, 110592);
    cvt_kernel<<<144, 256, 0, stream>>>(projw, wp, 36864);
    cvt_kernel<<<576, 256, 0, stream>>>(fc1w, w1, 147456);
    cvt_kernel<<<576, 256, 0, stream>>>(fc2w, w2, 147456);
    bias_kernel<<<57, 256, 0, stream>>>(rpi, rpb, biasg);

    ln_kernel<<<2048, 256, 0, stream>>>(x, n1g, n1b, xw);
    for (int c = 0; c < nchunks; ++c) {
        const size_t tok0 = (size_t)c * cw * 49;
        gemm_bt<0, 0, bf16><<<dim3(3, cw * 49 / 128), 256, 0, stream>>>(
            xw + tok0 * 192, wq, qkvb, qbuf, nullptr, 576, 192, nullptr, nullptr, nullptr);
        attn_kernel<<<cw * 6 / 4, 256, 0, stream>>>(
            qbuf, mask, biasg, attno + tok0 * 192, c * cw);
    }
    if (fuse) {
        gemm_bt<1, 1, float><<<dim3(1, 1568), 256, 0, stream>>>(
            attno, wp, projb, x1, x, 192, 192, n2g, n2b, hbuf);
    } else {
        gemm_bt<1, 0, float><<<dim3(1, 1568), 256, 0, stream>>>(
            attno, wp, projb, x1, x, 192, 192, nullptr, nullptr, nullptr);
        ln_kernel<<<2048, 256, 0, stream>>>(x1, n2g, n2b, hbuf);
    }
    mlp_kernel<<<3136, 256, 0, stream>>>(hbuf, w1, fc1b, w2, fc2b, (float*)d_out);
}

// Round 5
// 928.335 us; speedup vs baseline: 1.5240x; 1.5240x over previous
//
#include <hip/hip_runtime.h>
#include <hip/hip_bf16.h>

typedef __hip_bfloat16 bf16;
typedef __attribute__((ext_vector_type(8))) short bh8;   // 8 bf16 (MFMA A/B frag)
typedef __attribute__((ext_vector_type(4))) float f4;    // MFMA C/D frag

#define TOKENS 200704   // 16*112*112 = 4096 windows * 49
#define CDIM   192

__device__ __forceinline__ void gload16(const bf16* g, bf16* l) {
    __builtin_amdgcn_global_load_lds((const __attribute__((address_space(1))) void*)g,
                                     (__attribute__((address_space(3))) void*)l,
                                     16, 0, 0);
}

__device__ __forceinline__ void stv(float* p, float v) { *p = v; }
__device__ __forceinline__ void stv(bf16* p, float v)  { *p = __float2bfloat16(v); }

// window-row -> token index ((b,hs,ws) shifted back by +3)
__device__ __forceinline__ int row2tok(int row) {
    int win = row / 49, n = row - win * 49;
    int b = win >> 8, rem = win & 255;
    int hs = (rem >> 4) * 7 + n / 7;
    int wsx = (rem & 15) * 7 + n % 7;
    int hh = hs + 3; if (hh >= 112) hh -= 112;
    int ww = wsx + 3; if (ww >= 112) ww -= 112;
    return (b * 112 + hh) * 112 + ww;
}

// ---- fp32 -> bf16 weight conversion ----
__global__ void cvt_kernel(const float* __restrict__ s, bf16* __restrict__ d, int n) {
    int i = blockIdx.x * 256 + threadIdx.x;
    if (i < n) d[i] = __float2bfloat16(s[i]);
}

// ---- bias precompute: biasg[h][i][j] = rpb_table[rpi[i*49+j]][h] (fp32) ----
__global__ void bias_kernel(const int* __restrict__ rpi, const float* __restrict__ tab,
                            float* __restrict__ bg) {
    int idx = blockIdx.x * 256 + threadIdx.x;
    if (idx < 6 * 2401) {
        int h = idx / 2401, ij = idx - h * 2401;
        bg[idx] = tab[rpi[ij] * 6 + h];
    }
}

// ---- LayerNorm (fp32 in, bf16 out); GATHER=1 adds shift(-3,-3) + window partition ----
template<int GATHER>
__global__ __launch_bounds__(256)
void ln_kernel(const float* __restrict__ src, const float* __restrict__ gw,
               const float* __restrict__ bw, bf16* __restrict__ dst) {
    const int lane = threadIdx.x & 63;
    const int gwv  = (blockIdx.x * 256 + threadIdx.x) >> 6;
    const int nwv  = (gridDim.x * 256) >> 6;
    const float g0 = gw[lane], g1 = gw[lane + 64], g2 = gw[lane + 128];
    const float b0 = bw[lane], b1 = bw[lane + 64], b2 = bw[lane + 128];
    for (int row = gwv; row < TOKENS; row += nwv) {
        const float* p = GATHER ? src + (size_t)row2tok(row) * CDIM
                                : src + (size_t)row * CDIM;
        float v0 = p[lane], v1 = p[lane + 64], v2 = p[lane + 128];
        float s = v0 + v1 + v2;
        float q = v0 * v0 + v1 * v1 + v2 * v2;
        #pragma unroll
        for (int o = 32; o; o >>= 1) { s += __shfl_xor(s, o, 64); q += __shfl_xor(q, o, 64); }
        float mean = s * (1.f / 192.f);
        float var  = q * (1.f / 192.f) - mean * mean;
        float rstd = rsqrtf(var + 1e-5f);
        bf16* d = dst + (size_t)row * CDIM;
        d[lane]       = __float2bfloat16((v0 - mean) * rstd * g0 + b0);
        d[lane + 64]  = __float2bfloat16((v1 - mean) * rstd * g1 + b1);
        d[lane + 128] = __float2bfloat16((v2 - mean) * rstd * g2 + b2);
    }
}

// ---- GEMM: C[M,N] = A[M,K] @ W[N,K]^T + bias (A,W bf16; bias/res fp32) ----
// EPI 0: plain->bf16 (qkv).  EPI 1: proj scatter+residual->fp32.
// BM=128, BN=192, BK=32; 4 waves, each 64x96 (4x6 frags 16x16x32).
// LDS tiles swizzled: source slot g^=(row>>1)&3 at staging, read slot q^((r>>1)&3).
template<int EPI, typename OutT>
__global__ __launch_bounds__(256)
void gemm_bt(const bf16* __restrict__ A, const bf16* __restrict__ W,
             const float* __restrict__ bias, OutT* out,
             const float* res, int N, int K) {
    __shared__ __align__(16) bf16 As[128 * 32];
    __shared__ __align__(16) bf16 Bs[192 * 32];
    const int tid = threadIdx.x, wid = tid >> 6, lane = tid & 63;
    const int mbase = blockIdx.y * 128, nbase = blockIdx.x * 192;
    const int wm = wid >> 1, wn = wid & 1;
    const int r = lane & 15, q = lane >> 4;
    const int sx = (q ^ ((r >> 1) & 3)) << 3;   // swizzled read slot (elements)
    const bf16* Ab = A + (size_t)mbase * K;
    const bf16* Wb = W + (size_t)nbase * K;
    f4 acc[4][6] = {};
    const int cbase = wid * 64 + lane;
    for (int k0 = 0; k0 < K; k0 += 32) {
        #pragma unroll
        for (int p = 0; p < 2; ++p) {   // A tile: 128x32 = 512 chunks of 16B
            int ci = p * 256 + cbase;
            int row = ci >> 2, g = (ci & 3) ^ ((row >> 1) & 3);
            gload16(Ab + (size_t)row * K + (k0 + (g << 3)),
                    &As[(p * 256 + wid * 64) * 8]);
        }
        #pragma unroll
        for (int p = 0; p < 3; ++p) {   // B tile: 192x32 = 768 chunks of 16B
            int ci = p * 256 + cbase;
            int row = ci >> 2, g = (ci & 3) ^ ((row >> 1) & 3);
            gload16(Wb + (size_t)row * K + (k0 + (g << 3)),
                    &Bs[(p * 256 + wid * 64) * 8]);
        }
        __syncthreads();
        bh8 af[4], bfr[6];
        #pragma unroll
        for (int i = 0; i < 4; ++i)
            af[i] = *(const bh8*)&As[(wm * 64 + i * 16 + r) * 32 + sx];
        #pragma unroll
        for (int j = 0; j < 6; ++j)
            bfr[j] = *(const bh8*)&Bs[(wn * 96 + j * 16 + r) * 32 + sx];
        #pragma unroll
        for (int i = 0; i < 4; ++i)
            #pragma unroll
            for (int j = 0; j < 6; ++j)
                acc[i][j] = __builtin_amdgcn_mfma_f32_16x16x32_bf16(af[i], bfr[j], acc[i][j], 0, 0, 0);
        __syncthreads();
    }
    // epilogue: C/D frag layout col = lane&15, row = (lane>>4)*4 + reg
    const int cr = q, cc = r;
    #pragma unroll
    for (int i = 0; i < 4; ++i) {
        size_t dstRow[4];
        #pragma unroll
        for (int rr = 0; rr < 4; ++rr) {
            int row = mbase + wm * 64 + i * 16 + cr * 4 + rr;
            dstRow[rr] = (EPI == 1) ? (size_t)row2tok(row) * CDIM : (size_t)row * N;
        }
        #pragma unroll
        for (int j = 0; j < 6; ++j) {
            int ncol = nbase + wn * 96 + j * 16 + cc;
            float bv = bias[ncol];
            #pragma unroll
            for (int rr = 0; rr < 4; ++rr) {
                float v = acc[i][j][rr] + bv;
                size_t di = dstRow[rr] + ncol;
                if constexpr (EPI == 1) v += res[di];
                stv(&out[di], v);
            }
        }
    }
}

// ---- attention: one wave per (local window, head); in-register softmax ----
__global__ __launch_bounds__(256)
void attn_kernel(const bf16* __restrict__ qkv, const float* __restrict__ mask,
                 const float* __restrict__ biasg, bf16* __restrict__ out, int woff) {
    __shared__ float kv[4][2][49][32];   // 50176 B
    const int wid = threadIdx.x >> 6, lane = threadIdx.x & 63;
    const int task = blockIdx.x * 4 + wid;
    const int win = task / 6;                 // local window within chunk
    const int head = task - win * 6;
    const bf16* base = qkv + (size_t)win * 49 * 576 + head * 32;
    for (int idx = lane; idx < 49 * 32; idx += 64) {
        int j = idx >> 5, d = idx & 31;
        kv[wid][0][j][d] = __bfloat162float(base[j * 576 + 192 + d]);  // K
        kv[wid][1][j][d] = __bfloat162float(base[j * 576 + 384 + d]);  // V
    }
    __syncthreads();
    const int i = lane < 49 ? lane : 48;
    float q[32];
    #pragma unroll
    for (int d = 0; d < 32; ++d)
        q[d] = __bfloat162float(base[i * 576 + d]) * 0.17677669529663689f;  // 1/sqrt(32)
    const float* bg = biasg + head * 2401 + i * 49;
    const float* mk = mask + (size_t)((win + woff) & 255) * 2401 + i * 49;
    float s[49];
    float mx = -1e30f;
    #pragma unroll
    for (int j = 0; j < 49; ++j) {
        float a = 0.f;
        #pragma unroll
        for (int d = 0; d < 32; ++d) a += q[d] * kv[wid][0][j][d];
        a += bg[j] + mk[j];
        s[j] = a;
        mx = fmaxf(mx, a);
    }
    float sum = 0.f;
    #pragma unroll
    for (int j = 0; j < 49; ++j) { s[j] = __expf(s[j] - mx); sum += s[j]; }
    const float inv = 1.f / sum;
    float o[32];
    #pragma unroll
    for (int d = 0; d < 32; ++d) o[d] = 0.f;
    #pragma unroll
    for (int j = 0; j < 49; ++j) {
        float p = s[j] * inv;
        #pragma unroll
        for (int d = 0; d < 32; ++d) o[d] += p * kv[wid][1][j][d];
    }
    if (lane < 49) {
        bf16* op = out + ((size_t)win * 49 + lane) * CDIM + head * 32;
        #pragma unroll
        for (int d = 0; d < 32; ++d) op[d] = __float2bfloat16(o[d]);
    }
}

// ---- fused MLP: out[tok] += fc2(gelu(fc1(hbuf[tok]))) + b2 ; token order ----
// 128-row blocks, 1568 blocks, LDS 80 KiB -> 2 blocks/CU.
// Per chunk (12 x 64 fc1-cols): prefetch w1(12)+w2(12) frags -> GEMM1 -> GELU -> Hs[c&1]
// -> barrier -> GEMM2 accumulate.  One barrier per chunk (Hs ping-pong).
__global__ __launch_bounds__(256, 2)
void mlp_kernel(const bf16* __restrict__ Aht, const bf16* __restrict__ w1,
                const float* __restrict__ b1, const bf16* __restrict__ w2,
                const float* __restrict__ b2, float* __restrict__ out) {
    __shared__ __align__(16) bf16 As[6][128][32];   // 48 KiB, slot-swizzled
    __shared__ __align__(16) bf16 Hs[2][128][64];   // 32 KiB ping-pong, slot-swizzled
    const int tid = threadIdx.x, wid = tid >> 6, lane = tid & 63;
    const int mbase = blockIdx.x * 128;
    const int wm = wid >> 1, wn = wid & 1;
    const int r = lane & 15, q = lane >> 4, ko = q * 8;
    const int sxA = (q ^ ((r >> 1) & 3)) << 3;      // As read slot (elements)
    const int shH = r & 7;                          // Hs read-row swizzle key
    // stage A tile (swizzled source, linear dest)
    #pragma unroll
    for (int it = 0; it < 12; ++it) {
        int l = it * 256 + wid * 64 + lane;
        int ks = l >> 9, rem = l & 511, row = rem >> 2;
        int g = (rem & 3) ^ ((row >> 1) & 3);
        gload16(Aht + (size_t)(mbase + row) * 192 + ks * 32 + g * 8,
                &As[0][0][0] + (size_t)(it * 256 + wid * 64) * 8);
    }
    __syncthreads();
    f4 acc2[4][6] = {};
    for (int c = 0; c < 12; ++c) {
        const int cb = c * 64;
        // prefetch w1 fragments (12 x 16B, independent loads)
        bh8 w1f[6][2];
        #pragma unroll
        for (int ks = 0; ks < 6; ++ks)
            #pragma unroll
            for (int jn = 0; jn < 2; ++jn)
                w1f[ks][jn] = *(const bh8*)&w1[(size_t)(cb + wn * 32 + jn * 16 + r) * 192 + ks * 32 + ko];
        f4 acc1[4][2] = {};
        #pragma unroll
        for (int ks = 0; ks < 6; ++ks) {
            #pragma unroll
            for (int i = 0; i < 4; ++i) {
                bh8 af = *(const bh8*)(&As[ks][0][0] + (wm * 64 + i * 16 + r) * 32 + sxA);
                #pragma unroll
                for (int jn = 0; jn < 2; ++jn)
                    acc1[i][jn] = __builtin_amdgcn_mfma_f32_16x16x32_bf16(af, w1f[ks][jn], acc1[i][jn], 0, 0, 0);
            }
        }
        // prefetch w2 fragments for GEMM2 (12 x 16B)
        bh8 w2f[2][6];
        #pragma unroll
        for (int k2 = 0; k2 < 2; ++k2)
            #pragma unroll
            for (int j = 0; j < 6; ++j)
                w2f[k2][j] = *(const bh8*)&w2[(size_t)(wn * 96 + j * 16 + r) * 768 + cb + k2 * 32 + ko];
        const float b1v0 = b1[cb + wn * 32 + r];
        const float b1v1 = b1[cb + wn * 32 + 16 + r];
        bf16 (*Hp)[64] = Hs[c & 1];
        #pragma unroll
        for (int i = 0; i < 4; ++i) {
            #pragma unroll
            for (int jn = 0; jn < 2; ++jn) {
                #pragma unroll
                for (int rr = 0; rr < 4; ++rr) {
                    int row = wm * 64 + i * 16 + q * 4 + rr;
                    int col = wn * 32 + jn * 16 + r;
                    float v = acc1[i][jn][rr] + (jn ? b1v1 : b1v0);
                    float u = v * (0.7978845608f + 0.0356774081f * v * v);  // sqrt(2/pi)*(v+0.044715v^3)
                    float e = __expf(2.f * u);
                    float t = 1.f - 2.f / (e + 1.f);                        // tanh(u)
                    Hp[row][(((col >> 3) ^ (row & 7)) << 3) | (col & 7)] =
                        __float2bfloat16(0.5f * v * (1.f + t));
                }
            }
        }
        __syncthreads();
        #pragma unroll
        for (int k2 = 0; k2 < 2; ++k2) {
            #pragma unroll
            for (int i = 0; i < 4; ++i) {
                int row = wm * 64 + i * 16 + r;
                bh8 af = *(const bh8*)(&Hp[row][0] + ((((k2 * 4 + q) ^ shH) & 7) << 3));
                #pragma unroll
                for (int j = 0; j < 6; ++j)
                    acc2[i][j] = __builtin_amdgcn_mfma_f32_16x16x32_bf16(af, w2f[k2][j], acc2[i][j], 0, 0, 0);
            }
        }
    }
    // epilogue: coalesced fp32 RMW, token order
    #pragma unroll
    for (int i = 0; i < 4; ++i) {
        #pragma unroll
        for (int j = 0; j < 6; ++j) {
            int ncol = wn * 96 + j * 16 + r;
            float bv = b2[ncol];
            #pragma unroll
            for (int rr = 0; rr < 4; ++rr) {
                size_t idx = (size_t)(mbase + wm * 64 + i * 16 + q * 4 + rr) * 192 + ncol;
                out[idx] = acc2[i][j][rr] + bv + out[idx];
            }
        }
    }
}

extern "C" void kernel_launch(void* const* d_in, const int* in_sizes, int n_in,
                              void* d_out, int out_size, void* d_ws, size_t ws_size,
                              hipStream_t stream) {
    const float* x     = (const float*)d_in[0];
    const float* mask  = (const float*)d_in[1];
    const int*   rpi   = (const int*)d_in[2];
    const float* rpb   = (const float*)d_in[3];
    const float* n1g   = (const float*)d_in[4];
    const float* n1b   = (const float*)d_in[5];
    const float* qkvw  = (const float*)d_in[6];
    const float* qkvb  = (const float*)d_in[7];
    const float* projw = (const float*)d_in[8];
    const float* projb = (const float*)d_in[9];
    const float* n2g   = (const float*)d_in[10];
    const float* n2b   = (const float*)d_in[11];
    const float* fc1w  = (const float*)d_in[12];
    const float* fc1b  = (const float*)d_in[13];
    const float* fc2w  = (const float*)d_in[14];
    const float* fc2b  = (const float*)d_in[15];

    // ws layout:
    //  [0, 77,070,336)            attno bf16 (window order) -> later hbuf (ln2 out, token order)
    //  [77,070,336, 77,131,776)   biasg fp32
    //  [77,131,776, 78,016,512)   bf16 weights (wq|wp|w1|w2)
    //  [78,016,512, +cw*56448)    qbuf (qkv chunk)
    char* ws = (char*)d_ws;
    bf16*  attno  = (bf16*)ws;
    bf16*  hbuf   = (bf16*)ws;
    float* biasg  = (float*)(ws + 77070336);
    bf16*  wq     = (bf16*)(ws + 77131776);
    bf16*  wp     = (bf16*)(ws + 77352960);
    bf16*  w1     = (bf16*)(ws + 77426688);
    bf16*  w2     = (bf16*)(ws + 77721600);
    bf16*  qbuf   = (bf16*)(ws + 78016512);
    bf16*  xw     = (bf16*)d_out;    // LN1 out lives in d_out until proj overwrites it
    float* x1     = (float*)d_out;

    int cw = 1024;
    while (cw > 128 && 78016512ull + (size_t)cw * 56448 > ws_size) cw >>= 1;
    const int nchunks = 4096 / cw;

    cvt_kernel<<<432, 256, 0, stream>>>(qkvw, wq, 110592);
    cvt_kernel<<<144, 256, 0, stream>>>(projw, wp, 36864);
    cvt_kernel<<<576, 256, 0, stream>>>(fc1w, w1, 147456);
    cvt_kernel<<<576, 256, 0, stream>>>(fc2w, w2, 147456);
    bias_kernel<<<57, 256, 0, stream>>>(rpi, rpb, biasg);

    ln_kernel<1><<<2048, 256, 0, stream>>>(x, n1g, n1b, xw);
    for (int c = 0; c < nchunks; ++c) {
        const size_t tok0 = (size_t)c * cw * 49;
        gemm_bt<0, bf16><<<dim3(3, cw * 49 / 128), 256, 0, stream>>>(
            xw + tok0 * 192, wq, qkvb, qbuf, nullptr, 576, 192);
        attn_kernel<<<cw * 6 / 4, 256, 0, stream>>>(
            qbuf, mask, biasg, attno + tok0 * 192, c * cw);
    }
    gemm_bt<1, float><<<dim3(1, 1568), 256, 0, stream>>>(attno, wp, projb, x1, x, 192, 192);
    ln_kernel<0><<<2048, 256, 0, stream>>>(x1, n2g, n2b, hbuf);
    mlp_kernel<<<1568, 256, 0, stream>>>(hbuf, w1, fc1b, w2, fc2b, (float*)d_out);
}

// Round 6
// 896.678 us; speedup vs baseline: 1.5778x; 1.0353x over previous
//
#include <hip/hip_runtime.h>
#include <hip/hip_bf16.h>

typedef __hip_bfloat16 bf16;
typedef __attribute__((ext_vector_type(8))) short bh8;   // 8 bf16 (MFMA A/B frag)
typedef __attribute__((ext_vector_type(4))) float f4;    // MFMA C/D frag

#define TOKENS 200704   // 16*112*112 = 4096 windows * 49
#define CDIM   192

__device__ __forceinline__ void gload16(const bf16* g, bf16* l) {
    __builtin_amdgcn_global_load_lds((const __attribute__((address_space(1))) void*)g,
                                     (__attribute__((address_space(3))) void*)l,
                                     16, 0, 0);
}

__device__ __forceinline__ void stv(float* p, float v) { *p = v; }
__device__ __forceinline__ void stv(bf16* p, float v)  { *p = __float2bfloat16(v); }
__device__ __forceinline__ float b2f(short s) {
    return __uint_as_float(((unsigned)(unsigned short)s) << 16);
}

// window-row -> token index ((b,hs,ws) shifted back by +3)
__device__ __forceinline__ int row2tok(int row) {
    int win = row / 49, n = row - win * 49;
    int b = win >> 8, rem = win & 255;
    int hs = (rem >> 4) * 7 + n / 7;
    int wsx = (rem & 15) * 7 + n % 7;
    int hh = hs + 3; if (hh >= 112) hh -= 112;
    int ww = wsx + 3; if (ww >= 112) ww -= 112;
    return (b * 112 + hh) * 112 + ww;
}

// ---- fp32 -> bf16 conversion of all four weight matrices (contiguous dst) ----
__global__ void cvt_all(const float* __restrict__ a, const float* __restrict__ b,
                        const float* __restrict__ c, const float* __restrict__ d,
                        bf16* __restrict__ dst) {
    int i = blockIdx.x * 256 + threadIdx.x;
    if (i >= 442368) return;
    float v;
    if (i < 110592)       v = a[i];
    else if (i < 147456)  v = b[i - 110592];
    else if (i < 294912)  v = c[i - 147456];
    else                  v = d[i - 294912];
    dst[i] = __float2bfloat16(v);
}

// ---- combined bias+mask: bm[cls][h][i][j] = rpb[rpi[ij]][h] + mask[rep(cls)][ij] ----
// masks depend only on (wh==15, ww==15) -> 4 classes, reps {0,15,240,255}
__global__ void bias_bm_kernel(const int* __restrict__ rpi, const float* __restrict__ tab,
                               const float* __restrict__ mask, float* __restrict__ bm) {
    int idx = blockIdx.x * 256 + threadIdx.x;
    if (idx >= 4 * 6 * 2401) return;
    int cls = idx / 14406, r2 = idx - cls * 14406;
    int h = r2 / 2401, ij = r2 - h * 2401;
    int rep = ((cls & 2) ? 240 : 0) + ((cls & 1) ? 15 : 0);
    bm[idx] = tab[rpi[ij] * 6 + h] + mask[rep * 2401 + ij];
}

// ---- LayerNorm (fp32 in, bf16 out); GATHER=1 adds shift(-3,-3) + window partition ----
template<int GATHER>
__global__ __launch_bounds__(256)
void ln_kernel(const float* __restrict__ src, const float* __restrict__ gw,
               const float* __restrict__ bw, bf16* __restrict__ dst) {
    const int lane = threadIdx.x & 63;
    const int gwv  = (blockIdx.x * 256 + threadIdx.x) >> 6;
    const int nwv  = (gridDim.x * 256) >> 6;
    const float g0 = gw[lane], g1 = gw[lane + 64], g2 = gw[lane + 128];
    const float b0 = bw[lane], b1 = bw[lane + 64], b2 = bw[lane + 128];
    for (int row = gwv; row < TOKENS; row += nwv) {
        const float* p = GATHER ? src + (size_t)row2tok(row) * CDIM
                                : src + (size_t)row * CDIM;
        float v0 = p[lane], v1 = p[lane + 64], v2 = p[lane + 128];
        float s = v0 + v1 + v2;
        float q = v0 * v0 + v1 * v1 + v2 * v2;
        #pragma unroll
        for (int o = 32; o; o >>= 1) { s += __shfl_xor(s, o, 64); q += __shfl_xor(q, o, 64); }
        float mean = s * (1.f / 192.f);
        float var  = q * (1.f / 192.f) - mean * mean;
        float rstd = rsqrtf(var + 1e-5f);
        bf16* d = dst + (size_t)row * CDIM;
        d[lane]       = __float2bfloat16((v0 - mean) * rstd * g0 + b0);
        d[lane + 64]  = __float2bfloat16((v1 - mean) * rstd * g1 + b1);
        d[lane + 128] = __float2bfloat16((v2 - mean) * rstd * g2 + b2);
    }
}

// ---- GEMM: C[M,N] = A[M,K] @ W[N,K]^T + bias (A,W bf16; bias/res fp32) ----
// EPI 0: plain->bf16 (qkv).  EPI 1: proj scatter+residual->fp32.
// BM=128, BN=192, BK=32; 4 waves, each 64x96 (4x6 frags 16x16x32); swizzled LDS.
template<int EPI, typename OutT>
__global__ __launch_bounds__(256)
void gemm_bt(const bf16* __restrict__ A, const bf16* __restrict__ W,
             const float* __restrict__ bias, OutT* out,
             const float* res, int N, int K) {
    __shared__ __align__(16) bf16 As[128 * 32];
    __shared__ __align__(16) bf16 Bs[192 * 32];
    const int tid = threadIdx.x, wid = tid >> 6, lane = tid & 63;
    const int mbase = blockIdx.y * 128, nbase = blockIdx.x * 192;
    const int wm = wid >> 1, wn = wid & 1;
    const int r = lane & 15, q = lane >> 4;
    const int sx = (q ^ ((r >> 1) & 3)) << 3;   // swizzled read slot (elements)
    const bf16* Ab = A + (size_t)mbase * K;
    const bf16* Wb = W + (size_t)nbase * K;
    f4 acc[4][6] = {};
    const int cbase = wid * 64 + lane;
    for (int k0 = 0; k0 < K; k0 += 32) {
        #pragma unroll
        for (int p = 0; p < 2; ++p) {   // A tile: 128x32 = 512 chunks of 16B
            int ci = p * 256 + cbase;
            int row = ci >> 2, g = (ci & 3) ^ ((row >> 1) & 3);
            gload16(Ab + (size_t)row * K + (k0 + (g << 3)),
                    &As[(p * 256 + wid * 64) * 8]);
        }
        #pragma unroll
        for (int p = 0; p < 3; ++p) {   // B tile: 192x32 = 768 chunks of 16B
            int ci = p * 256 + cbase;
            int row = ci >> 2, g = (ci & 3) ^ ((row >> 1) & 3);
            gload16(Wb + (size_t)row * K + (k0 + (g << 3)),
                    &Bs[(p * 256 + wid * 64) * 8]);
        }
        __syncthreads();
        bh8 af[4], bfr[6];
        #pragma unroll
        for (int i = 0; i < 4; ++i)
            af[i] = *(const bh8*)&As[(wm * 64 + i * 16 + r) * 32 + sx];
        #pragma unroll
        for (int j = 0; j < 6; ++j)
            bfr[j] = *(const bh8*)&Bs[(wn * 96 + j * 16 + r) * 32 + sx];
        #pragma unroll
        for (int i = 0; i < 4; ++i)
            #pragma unroll
            for (int j = 0; j < 6; ++j)
                acc[i][j] = __builtin_amdgcn_mfma_f32_16x16x32_bf16(af[i], bfr[j], acc[i][j], 0, 0, 0);
        __syncthreads();
    }
    const int cr = q, cc = r;
    #pragma unroll
    for (int i = 0; i < 4; ++i) {
        size_t dstRow[4];
        #pragma unroll
        for (int rr = 0; rr < 4; ++rr) {
            int row = mbase + wm * 64 + i * 16 + cr * 4 + rr;
            dstRow[rr] = (EPI == 1) ? (size_t)row2tok(row) * CDIM : (size_t)row * N;
        }
        #pragma unroll
        for (int j = 0; j < 6; ++j) {
            int ncol = nbase + wn * 96 + j * 16 + cc;
            float bv = bias[ncol];
            #pragma unroll
            for (int rr = 0; rr < 4; ++rr) {
                float v = acc[i][j][rr] + bv;
                size_t di = dstRow[rr] + ncol;
                if constexpr (EPI == 1) v += res[di];
                stv(&out[di], v);
            }
        }
    }
}

// ---- attention: one wave per (local window, head); uniform-broadcast f4 LDS reads ----
__global__ __launch_bounds__(256)
void attn_kernel(const bf16* __restrict__ qkv, const float* __restrict__ bm,
                 bf16* __restrict__ out, int woff) {
    __shared__ __align__(16) float kv[4][2][49][32];   // 50176 B
    const int wid = threadIdx.x >> 6, lane = threadIdx.x & 63;
    const int task = blockIdx.x * 4 + wid;
    const int win = task / 6;                 // local window within chunk
    const int head = task - win * 6;
    const bf16* kbase = qkv + (size_t)win * 49 * 576 + head * 32 + 192;
    // stage K,V: 196 16B-chunks each, bh8 loads + f4 LDS writes
    #pragma unroll
    for (int it = 0; it < 4; ++it) {
        int lc = it * 64 + lane;
        if (lc < 196) {
            int row = lc >> 2, g = lc & 3;
            bh8 k8 = *(const bh8*)&kbase[row * 576 + g * 8];
            bh8 v8 = *(const bh8*)&kbase[row * 576 + 192 + g * 8];
            f4 klo, khi, vlo, vhi;
            #pragma unroll
            for (int e = 0; e < 4; ++e) {
                klo[e] = b2f(k8[e]); khi[e] = b2f(k8[e + 4]);
                vlo[e] = b2f(v8[e]); vhi[e] = b2f(v8[e + 4]);
            }
            *(f4*)&kv[wid][0][row][g * 8]     = klo;
            *(f4*)&kv[wid][0][row][g * 8 + 4] = khi;
            *(f4*)&kv[wid][1][row][g * 8]     = vlo;
            *(f4*)&kv[wid][1][row][g * 8 + 4] = vhi;
        }
    }
    __syncthreads();
    const int i = lane < 49 ? lane : 48;
    const bf16* qbase = qkv + (size_t)win * 49 * 576 + head * 32 + (size_t)i * 576;
    float q[32];
    #pragma unroll
    for (int t = 0; t < 4; ++t) {
        bh8 q8 = *(const bh8*)&qbase[t * 8];
        #pragma unroll
        for (int e = 0; e < 8; ++e)
            q[t * 8 + e] = b2f(q8[e]) * 0.17677669529663689f;   // 1/sqrt(32)
    }
    int rem = (win + woff) & 255;
    int cls = (((rem >> 4) == 15) ? 2 : 0) + (((rem & 15) == 15) ? 1 : 0);
    const float* bmp = bm + (size_t)(cls * 6 + head) * 2401 + i * 49;
    const f4* kp = (const f4*)&kv[wid][0][0][0];
    const f4* vp = (const f4*)&kv[wid][1][0][0];
    float s[49];
    float mx = -1e30f;
    #pragma unroll
    for (int j = 0; j < 49; ++j) {
        float a = 0.f;
        #pragma unroll
        for (int dq = 0; dq < 8; ++dq) {
            f4 kf = kp[j * 8 + dq];   // uniform address -> broadcast
            a += q[dq * 4] * kf[0] + q[dq * 4 + 1] * kf[1]
               + q[dq * 4 + 2] * kf[2] + q[dq * 4 + 3] * kf[3];
        }
        a += bmp[j];
        s[j] = a;
        mx = fmaxf(mx, a);
    }
    float sum = 0.f;
    #pragma unroll
    for (int j = 0; j < 49; ++j) { s[j] = __expf(s[j] - mx); sum += s[j]; }
    const float inv = 1.f / sum;
    f4 o4[8] = {};
    #pragma unroll
    for (int j = 0; j < 49; ++j) {
        float p = s[j] * inv;
        #pragma unroll
        for (int dq = 0; dq < 8; ++dq) {
            f4 vf = vp[j * 8 + dq];
            o4[dq][0] += p * vf[0]; o4[dq][1] += p * vf[1];
            o4[dq][2] += p * vf[2]; o4[dq][3] += p * vf[3];
        }
    }
    if (lane < 49) {
        bf16* op = out + ((size_t)win * 49 + lane) * CDIM + head * 32;
        #pragma unroll
        for (int t = 0; t < 4; ++t) {
            bh8 w;
            #pragma unroll
            for (int e = 0; e < 8; ++e) {
                bf16 h = __float2bfloat16(o4[t * 2 + (e >> 2)][e & 3]);
                w[e] = *(short*)&h;
            }
            *(bh8*)&op[t * 8] = w;
        }
    }
}

// ---- fused MLP: out[tok] += fc2(gelu(fc1(hbuf[tok]))) + b2 ; token order ----
// 64-row blocks, 4 waves, 40 KiB LDS (As 24K + Hs 16K pingpong) -> 4 blocks/CU.
// Per chunk (12 x 64 fc1-cols): w1 prefetch -> GEMM1 -> w2 prefetch -> GELU -> Hs[c&1]
// -> barrier -> GEMM2 accumulate.  One barrier per chunk.
__global__ __launch_bounds__(256, 4)
void mlp_kernel(const bf16* __restrict__ Aht, const bf16* __restrict__ w1,
                const float* __restrict__ b1, const bf16* __restrict__ w2,
                const float* __restrict__ b2, float* __restrict__ out) {
    __shared__ __align__(16) bf16 As[6][64][32];   // 24 KiB, slot-swizzled
    __shared__ __align__(16) bf16 Hs[2][64][64];   // 16 KiB ping-pong, slot-swizzled
    const int tid = threadIdx.x, wid = tid >> 6, lane = tid & 63;
    const int mbase = blockIdx.x * 64;
    const int r = lane & 15, q = lane >> 4, ko = q * 8;
    const int sxA = (q ^ ((r >> 1) & 3)) << 3;      // As read slot (elements)
    // stage A tile: 1536 16B-chunks (swizzled source, linear dest)
    #pragma unroll
    for (int it = 0; it < 6; ++it) {
        int l = it * 256 + wid * 64 + lane;
        int ks = l >> 8, rem2 = l & 255, row = rem2 >> 2;
        int g = (rem2 & 3) ^ ((row >> 1) & 3);
        gload16(Aht + (size_t)(mbase + row) * 192 + ks * 32 + g * 8,
                &As[0][0][0] + (size_t)(it * 256 + wid * 64) * 8);
    }
    __syncthreads();
    f4 acc2[4][3] = {};
    for (int c = 0; c < 12; ++c) {
        const int cb = c * 64;
        bh8 w1f[6];
        #pragma unroll
        for (int ks = 0; ks < 6; ++ks)
            w1f[ks] = *(const bh8*)&w1[(size_t)(cb + wid * 16 + r) * 192 + ks * 32 + ko];
        f4 acc1[4] = {};
        #pragma unroll
        for (int ks = 0; ks < 6; ++ks)
            #pragma unroll
            for (int i = 0; i < 4; ++i) {
                bh8 af = *(const bh8*)(&As[ks][0][0] + (i * 16 + r) * 32 + sxA);
                acc1[i] = __builtin_amdgcn_mfma_f32_16x16x32_bf16(af, w1f[ks], acc1[i], 0, 0, 0);
            }
        bh8 w2f[2][3];
        #pragma unroll
        for (int k2 = 0; k2 < 2; ++k2)
            #pragma unroll
            for (int j = 0; j < 3; ++j)
                w2f[k2][j] = *(const bh8*)&w2[(size_t)(wid * 48 + j * 16 + r) * 768 + cb + k2 * 32 + ko];
        const float b1v = b1[cb + wid * 16 + r];
        bf16 (*Hp)[64] = Hs[c & 1];
        #pragma unroll
        for (int i = 0; i < 4; ++i) {
            #pragma unroll
            for (int rr = 0; rr < 4; ++rr) {
                int row = i * 16 + q * 4 + rr;
                int col = wid * 16 + r;
                float v = acc1[i][rr] + b1v;
                float u = v * (1.5957691216f + 0.0713548162f * v * v);   // 2*sqrt(2/pi)*(v+0.044715v^3)
                float e = __expf(u);
                Hp[row][(((col >> 3) ^ (row & 7)) << 3) | (col & 7)] =
                    __float2bfloat16(v * e / (e + 1.f));                 // v*sigmoid(u) = gelu_tanh
            }
        }
        __syncthreads();
        #pragma unroll
        for (int k2 = 0; k2 < 2; ++k2)
            #pragma unroll
            for (int i = 0; i < 4; ++i) {
                int row = i * 16 + r;
                bh8 af = *(const bh8*)(&Hp[row][0] + ((((k2 * 4 + q) ^ (row & 7)) & 7) << 3));
                #pragma unroll
                for (int j = 0; j < 3; ++j)
                    acc2[i][j] = __builtin_amdgcn_mfma_f32_16x16x32_bf16(af, w2f[k2][j], acc2[i][j], 0, 0, 0);
            }
    }
    // epilogue: coalesced fp32 RMW
    #pragma unroll
    for (int i = 0; i < 4; ++i) {
        #pragma unroll
        for (int j = 0; j < 3; ++j) {
            int ncol = wid * 48 + j * 16 + r;
            float bv = b2[ncol];
            #pragma unroll
            for (int rr = 0; rr < 4; ++rr) {
                size_t idx = (size_t)(mbase + i * 16 + q * 4 + rr) * 192 + ncol;
                out[idx] = acc2[i][j][rr] + bv + out[idx];
            }
        }
    }
}

extern "C" void kernel_launch(void* const* d_in, const int* in_sizes, int n_in,
                              void* d_out, int out_size, void* d_ws, size_t ws_size,
                              hipStream_t stream) {
    const float* x     = (const float*)d_in[0];
    const float* mask  = (const float*)d_in[1];
    const int*   rpi   = (const int*)d_in[2];
    const float* rpb   = (const float*)d_in[3];
    const float* n1g   = (const float*)d_in[4];
    const float* n1b   = (const float*)d_in[5];
    const float* qkvw  = (const float*)d_in[6];
    const float* qkvb  = (const float*)d_in[7];
    const float* projw = (const float*)d_in[8];
    const float* projb = (const float*)d_in[9];
    const float* n2g   = (const float*)d_in[10];
    const float* n2b   = (const float*)d_in[11];
    const float* fc1w  = (const float*)d_in[12];
    const float* fc1b  = (const float*)d_in[13];
    const float* fc2w  = (const float*)d_in[14];
    const float* fc2b  = (const float*)d_in[15];

    // ws layout:
    //  [0, 77,070,336)            attno bf16 (window order) -> later hbuf (ln2 out)
    //  [77,070,336, 77,300,832)   bm fp32 (4x6x2401)
    //  [77,300,832, 78,185,568)   bf16 weights contiguous (wq|wp|w1|w2)
    //  [78,185,568, +cw*56448)    qbuf (qkv chunk)
    char* ws = (char*)d_ws;
    bf16*  attno  = (bf16*)ws;
    bf16*  hbuf   = (bf16*)ws;
    float* bm     = (float*)(ws + 77070336);
    bf16*  wq     = (bf16*)(ws + 77300832);
    bf16*  wp     = (bf16*)(ws + 77522016);
    bf16*  w1     = (bf16*)(ws + 77595744);
    bf16*  w2     = (bf16*)(ws + 77890656);
    bf16*  qbuf   = (bf16*)(ws + 78185568);
    bf16*  xw     = (bf16*)d_out;    // LN1 out lives in d_out until proj overwrites it
    float* x1     = (float*)d_out;

    int cw = 1024;
    while (cw > 128 && 78185568ull + (size_t)cw * 56448 > ws_size) cw >>= 1;
    const int nchunks = 4096 / cw;

    cvt_all<<<1728, 256, 0, stream>>>(qkvw, projw, fc1w, fc2w, wq);
    bias_bm_kernel<<<226, 256, 0, stream>>>(rpi, rpb, mask, bm);

    ln_kernel<1><<<2048, 256, 0, stream>>>(x, n1g, n1b, xw);
    for (int c = 0; c < nchunks; ++c) {
        const size_t tok0 = (size_t)c * cw * 49;
        gemm_bt<0, bf16><<<dim3(3, cw * 49 / 128), 256, 0, stream>>>(
            xw + tok0 * 192, wq, qkvb, qbuf, nullptr, 576, 192);
        attn_kernel<<<cw * 6 / 4, 256, 0, stream>>>(
            qbuf, bm, attno + tok0 * 192, c * cw);
    }
    gemm_bt<1, float><<<dim3(1, 1568), 256, 0, stream>>>(attno, wp, projb, x1, x, 192, 192);
    ln_kernel<0><<<2048, 256, 0, stream>>>(x1, n2g, n2b, hbuf);
    mlp_kernel<<<3136, 256, 0, stream>>>(hbuf, w1, fc1b, w2, fc2b, (float*)d_out);
}